// Round 7
// baseline (4730.990 us; speedup 1.0000x reference)
//
#include <hip/hip_runtime.h>

typedef unsigned short u16;
typedef __attribute__((ext_vector_type(8))) unsigned short ushort8;
typedef __attribute__((ext_vector_type(4))) float f32x4;
typedef __attribute__((ext_vector_type(8))) __bf16 bf16x8;

#define N_B 256
#define LSEQ 128
#define AROW 2304   // 768 (h1) + 2*768 (h2 double-buffer phases)
#define NBLK 256

#define MFMA_B16(a, b, c) __builtin_amdgcn_mfma_f32_16x16x32_bf16( \
    __builtin_bit_cast(bf16x8, a), __builtin_bit_cast(bf16x8, b), c, 0, 0, 0)

// plain cached staging (read-only weights)
#define GLLDS(gp, lp) __builtin_amdgcn_global_load_lds( \
    (const __attribute__((address_space(1))) void*)(gp), \
    (__attribute__((address_space(3))) void*)(lp), 16, 0, 0)
// coherent staging (mutable cross-block data): aux=17 = sc0|sc1
#define GLLDS_C(gp, lp) __builtin_amdgcn_global_load_lds( \
    (const __attribute__((address_space(1))) void*)(gp), \
    (__attribute__((address_space(3))) void*)(lp), 16, 0, 17)

#define ATOMIC_LD(p) __hip_atomic_load((p), __ATOMIC_RELAXED, __HIP_MEMORY_SCOPE_AGENT)
#define ATOMIC_ST(p, v) __hip_atomic_store((p), (v), __ATOMIC_RELAXED, __HIP_MEMORY_SCOPE_AGENT)

// ---- workspace layout (byte offsets) ----
#define OFF_BP2   0ull
#define SZ_BP2    (48ull*192*512*2)
#define OFF_BP1   (OFF_BP2 + SZ_BP2)
#define SZ_BP1    (24ull*192*512*2)
#define OFF_W1P   (OFF_BP1 + SZ_BP1)
#define SZ_W1P    (24ull*32*512*2)
#define OFF_WIH1T (OFF_W1P + SZ_W1P)
#define SZ_WIH1T  (9ull*3072*4)
#define OFF_BS1   (OFF_WIH1T + SZ_WIH1T)
#define OFF_BS2   (OFF_BS1 + 3072*4)
#define OFF_G1P   (OFF_BS2 + 3072*4)
#define SZ_G1P    (256ull*3072*4)
#define OFF_PBUF  (OFF_G1P + SZ_G1P)
#define SZ_PBUF   (256ull*8*4)
#define OFF_ZERO  (OFF_PBUF + SZ_PBUF)
#define OFF_ACAT  OFF_ZERO
#define SZ_ACAT   (256ull*2304*2)
#define OFF_C1    (OFF_ACAT + SZ_ACAT)
#define OFF_C2    (OFF_C1 + 256ull*768*4)
#define OFF_SB    (OFF_C2 + 256ull*768*4)
#define OFF_BAR   (OFF_SB + 1024)      // flags at bar+32: 4 clusters x 128 uints
#define SZ_BAR    (128 + 256*32*4)
#define OFF_END   (OFF_BAR + SZ_BAR)
#define ZERO_BYTES (OFF_END - OFF_ZERO)

__device__ __forceinline__ float sigf(float v) { return 1.f / (1.f + __expf(-v)); }
__device__ __forceinline__ float tanhfast(float v) { return 1.f - 2.f / (__expf(2.f * v) + 1.f); }
__device__ __forceinline__ u16 f2bf(float f) {
  union { float f; unsigned u; } v; v.f = f;
  unsigned r = v.u + 0x7fffu + ((v.u >> 16) & 1u);   // round-to-nearest-even
  return (u16)(r >> 16);
}

struct Params {
  const float* x;
  const u16* Bp2; const u16* Bp1; const u16* W1p;
  const float* Wih1t; const float* bs1; const float* bs2;
  const float* b1; const float* W2; const float* b2;
  u16* Acat; float* g1p; float* c1; float* c2; float* sb; float* pbuf;
  unsigned* bar;
  float* outs; float* stores;
};

// ---------------------------------------------------------------------------
// Dataflow sync (round-7 causal change): rows never interact, so the grid
// decomposes into 4 independent 64-row clusters. No global barrier exists;
// each producer sets a monotone per-block flag after vmcnt(0)-draining its
// sc1 data stores (round-6-proven visibility protocol), consumers poll the
// flags they need with one relaxed sc1 load per lane + __all. Per-cluster
// flag layout (cfl = bar+32+c*128): [0..31]=F, [32..47]=g1p, [48..95]=gates2,
// [96..111]=H. DAG per step: hdone(t-1) -> {gates2 || g1p} -> g2done -> F ->
// fdone -> H(+g1done) -> hdone(t). Buffer reuse is ordered by this DAG plus
// per-block program order (F-role blocks are gates2 blocks 0..31; H-role
// blocks are the g1p blocks 48..63). All 256 blocks co-resident -> no
// deadlock; monotone flags -> no reset races.
// ---------------------------------------------------------------------------
__device__ __forceinline__ void waitflags(const unsigned* f, int n, unsigned target, int tid) {
  if (tid < 64) {
    for (;;) {
      unsigned v = (tid < n) ? ATOMIC_LD(f + tid) : target;
      if (__all((int)(v >= target))) break;
      __builtin_amdgcn_s_sleep(1);
    }
  }
  __syncthreads();
}
__device__ __forceinline__ void setflag(unsigned* f, unsigned v) {
  asm volatile("s_waitcnt vmcnt(0)" ::: "memory");   // per-wave data-store drain
  __syncthreads();                                    // all waves drained
  if (threadIdx.x == 0) ATOMIC_ST(f, v);
}

// ---------------------------------------------------------------------------
// One-time packing: weights -> bf16 MFMA fragment layout (round-1 verified).
// ---------------------------------------------------------------------------
__global__ void pack_kernel(const float* __restrict__ Wih1, const float* __restrict__ bih1,
                            const float* __restrict__ Whh1, const float* __restrict__ bhh1,
                            const float* __restrict__ Wih2, const float* __restrict__ bih2,
                            const float* __restrict__ Whh2, const float* __restrict__ bhh2,
                            const float* __restrict__ W1,
                            u16* __restrict__ Bp2, u16* __restrict__ Bp1, u16* __restrict__ W1p,
                            float* __restrict__ Wih1t, float* __restrict__ bs1, float* __restrict__ bs2) {
  const long NB2 = 48l * 192 * 512, NB1 = 24l * 192 * 512, NW1 = 24l * 32 * 512, NT = 9l * 3072;
  const long total = NB2 + NB1 + NW1 + NT + 3072 * 2;
  for (long idx = (long)blockIdx.x * 256 + threadIdx.x; idx < total; idx += (long)gridDim.x * 256) {
    if (idx < NB2) {                       // Wcat2 = [W_ih2 ; W_hh2] (K=1536)
      long kt = idx / (192 * 512); long r = idx % (192 * 512);
      int jt = (int)(r / 512); int s = (int)(r % 512);
      int ll = s >> 3, e = s & 7;
      int k = (int)kt * 32 + ((ll >> 4) * 8) + e;
      int j = jt * 16 + (ll & 15);
      float v = (k < 768) ? Wih2[j * 768 + k] : Whh2[j * 768 + k - 768];
      Bp2[idx] = f2bf(v);
    } else if (idx < NB2 + NB1) {          // W_hh1 (K=768)
      long i = idx - NB2;
      long kt = i / (192 * 512); long r = i % (192 * 512);
      int jt = (int)(r / 512); int s = (int)(r % 512);
      int ll = s >> 3, e = s & 7;
      int k = (int)kt * 32 + ((ll >> 4) * 8) + e;
      int j = jt * 16 + (ll & 15);
      Bp1[i] = f2bf(Whh1[j * 768 + k]);
    } else if (idx < NB2 + NB1 + NW1) {    // W1 (K=768, N=512)
      long i = idx - NB2 - NB1;
      long kt = i / (32 * 512); long r = i % (32 * 512);
      int jt = (int)(r / 512); int s = (int)(r % 512);
      int ll = s >> 3, e = s & 7;
      int k = (int)kt * 32 + ((ll >> 4) * 8) + e;
      int j = jt * 16 + (ll & 15);
      W1p[i] = f2bf(W1[j * 768 + k]);
    } else if (idx < NB2 + NB1 + NW1 + NT) {  // W_ih1 transposed (fp32)
      long i = idx - NB2 - NB1 - NW1;
      int k = (int)(i / 3072), j = (int)(i % 3072);
      Wih1t[i] = Wih1[j * 9 + k];
    } else {
      long i = idx - NB2 - NB1 - NW1 - NT;
      if (i < 3072) bs1[i] = bih1[i] + bhh1[i];
      else { long j = i - 3072; bs2[j] = bih2[j] + bhh2[j]; }
    }
  }
}

// ---------------------------------------------------------------------------
// phase H: out-reduction, exact fp32 store integration, h1(t+1) activation.
// One block x 4 rows (n0). t == -1 bootstraps.
// ---------------------------------------------------------------------------
__device__ __forceinline__ void phase_H(const Params& P, int t, int tid, int n0,
                                        float (*xsb)[8]) {
  if (tid < 4) {
    int n = n0 + tid;
    float ov = 0.f;
    if (t >= 0) {
      float pb[8];
#pragma unroll
      for (int i = 0; i < 8; ++i) pb[i] = ATOMIC_LD(P.pbuf + n * 8 + i);
      ov = ((pb[0] + pb[1]) + (pb[2] + pb[3])) + ((pb[4] + pb[5]) + (pb[6] + pb[7])) + P.b2[0];
      P.outs[n * LSEQ + t] = ov;
    }
    if (t < 127) {
      float cs = P.sb[n] + P.x[(n * LSEQ + t + 1) * 8] - ov;   // exact fp32 integration
      P.sb[n] = cs;
      P.stores[n * LSEQ + t + 1] = cs;
      xsb[0][4 + tid] = cs;
    }
  }
  if (t == -1 && tid < 32)
    xsb[1 + (tid >> 3)][tid & 7] = P.x[((n0 + (tid >> 3)) * LSEQ) * 8 + (tid & 7)];
  __syncthreads();
  if (t >= 127) return;
  for (int p = tid; p < 1536; p += 256) {            // 4 rows x 384 col-pairs
    int r = p / 384, mp = (p - r * 384) * 2;
    int n = n0 + r;
    float cs = xsb[0][4 + r];
    float ga[4], gb[4];
#pragma unroll
    for (int q = 0; q < 4; ++q) {
      int j = mp + q * 768;
      float b0, b1;
      if (t >= 0) {
        union { unsigned long long u; float f[2]; } cv;
        cv.u = ATOMIC_LD((const unsigned long long*)(P.g1p + n * 3072 + j));
        b0 = cv.f[0]; b1 = cv.f[1];
      } else {
        b0 = P.bs1[j]; b1 = P.bs1[j + 1];
#pragma unroll
        for (int k = 0; k < 8; ++k) {
          b0 += xsb[1 + r][k] * P.Wih1t[k * 3072 + j];
          b1 += xsb[1 + r][k] * P.Wih1t[k * 3072 + j + 1];
        }
      }
      ga[q] = b0 + cs * P.Wih1t[8 * 3072 + j];
      gb[q] = b1 + cs * P.Wih1t[8 * 3072 + j + 1];
    }
    float co0 = P.c1[n * 768 + mp], co1 = P.c1[n * 768 + mp + 1];
    float cn0 = sigf(ga[1]) * co0 + sigf(ga[0]) * tanhfast(ga[2]);
    float cn1 = sigf(gb[1]) * co1 + sigf(gb[0]) * tanhfast(gb[2]);
    float h0 = sigf(ga[3]) * tanhfast(cn0);
    float h1 = sigf(gb[3]) * tanhfast(cn1);
    P.c1[n * 768 + mp] = cn0;
    P.c1[n * 768 + mp + 1] = cn1;
    unsigned pk = (unsigned)f2bf(h0) | ((unsigned)f2bf(h1) << 16);
    ATOMIC_ST((unsigned*)(P.Acat + n * AROW + mp), pk);
  }
}

// ---------------------------------------------------------------------------
// Persistent kernel: 4 independent 64-row clusters of 64 blocks each.
//   local 0..47 : gates2 (64 rows x 64 cols, K=1536) + h2/c2 update
//   local 0..31 : then F (FC partials, 16 rows x 64 cols)
//   local 48..63: g1p (64 rows x 192 cols, K=768), then H (4 rows)
// ---------------------------------------------------------------------------
__global__ __launch_bounds__(256) void lstm_fused(Params P) {
  __shared__ ushort8 sbuf[48 * 64];     // 48 KB: triple-buffered staging (3 x 16 frags)
  __shared__ float xsb[64][8];          // 2 KB
  float (*fbuf)[64][16] = (float(*)[64][16])sbuf;  // 16 KB overlay (bytes 0..16K)
  const int tid = threadIdx.x, l = tid & 63, w = tid >> 6;
  const int bid = blockIdx.x;
  const int c = bid >> 6, local = bid & 63;
  const int rowbase = c * 64;
  unsigned* cfl = P.bar + 32 + c * 128;

  if (local >= 48) {
    phase_H(P, -1, tid, rowbase + (local - 48) * 4, xsb);
    setflag(cfl + 96 + (local - 48), 1u);
  }

  for (int t = 0; t < 128; ++t) {
    waitflags(cfl + 96, 16, (unsigned)(t + 1), tid);    // H(t-1) done: h1(t), h2(t-1) ready

    if (local < 48) {
      // ---- gates2: 64 rows x (4 quadrants x 16 cols), K=1536 ----
      const int mg = local;
      const int rdbase = 768 + (t & 1) * 768;        // h2(t-1)
      const int wrbase = 768 + ((t + 1) & 1) * 768;  // h2(t)
      auto stage_g2 = [&](int kc, int slot) {
#pragma unroll
        for (int i = 0; i < 4; ++i) {
          int f = w * 4 + i;                         // wave-uniform fragment id
          if (f < 8) {                               // A (mutable): coherent
            int kt2 = f >> 2, rt = f & 3, kt = kc * 2 + kt2;
            int col = (kt >= 24) ? (rdbase + (kt - 24) * 32 + ((l >> 4) * 8))
                                 : (kt * 32 + ((l >> 4) * 8));
            const u16* gp = P.Acat + (rowbase + rt * 16 + (l & 15)) * AROW + col;
            GLLDS_C(gp, &sbuf[(slot * 16 + f) * 64]);
          } else {                                   // B (weights): plain cached
            int g = f - 8, kt2 = g >> 2, q = g & 3, kt = kc * 2 + kt2;
            const u16* gp = P.Bp2 + (((long)(kt * 192 + q * 48 + mg)) << 9) + l * 8;
            GLLDS(gp, &sbuf[(slot * 16 + f) * 64]);
          }
        }
      };
      f32x4 acc[4] = {};
      stage_g2(0, 0);
      stage_g2(1, 1);
      for (int kc = 0; kc < 24; ++kc) {
        if (kc < 22) {
          stage_g2(kc + 2, (kc + 2) % 3);
          asm volatile("s_waitcnt vmcnt(8)" ::: "memory");
        } else if (kc == 22) {
          asm volatile("s_waitcnt vmcnt(4)" ::: "memory");
        } else {
          asm volatile("s_waitcnt vmcnt(0)" ::: "memory");
        }
        __builtin_amdgcn_s_barrier();
        __builtin_amdgcn_sched_barrier(0);
        const int base = (kc % 3) * 16;
#pragma unroll
        for (int kt2 = 0; kt2 < 2; ++kt2) {
          ushort8 bfr = sbuf[(base + 8 + kt2 * 4 + w) * 64 + l];
#pragma unroll
          for (int rt = 0; rt < 4; ++rt) {
            ushort8 a = sbuf[(base + kt2 * 4 + rt) * 64 + l];
            acc[rt] = MFMA_B16(a, bfr, acc[rt]);
          }
        }
        __builtin_amdgcn_sched_barrier(0);
        __builtin_amdgcn_s_barrier();
      }
      // epilogue: quadrant exchange -> h2/c2 update
#pragma unroll
      for (int rt = 0; rt < 4; ++rt)
#pragma unroll
        for (int reg = 0; reg < 4; ++reg) {
          int rl = rt * 16 + (l >> 4) * 4 + reg;
          fbuf[w][rl][l & 15] = acc[rt][reg] + P.bs2[w * 768 + mg * 16 + (l & 15)];
        }
      __syncthreads();
      for (int p = tid; p < 512; p += 256) {         // 64 rows x 8 col-pairs
        int r = p >> 3, pp = (p & 7) * 2;
        int n = rowbase + r, mG = mg * 16 + pp;
        float gi0 = fbuf[0][r][pp], gi1 = fbuf[0][r][pp + 1];
        float gf0 = fbuf[1][r][pp], gf1 = fbuf[1][r][pp + 1];
        float gg0 = fbuf[2][r][pp], gg1 = fbuf[2][r][pp + 1];
        float go0 = fbuf[3][r][pp], go1 = fbuf[3][r][pp + 1];
        float co0 = P.c2[n * 768 + mG], co1 = P.c2[n * 768 + mG + 1];
        float cn0 = sigf(gf0) * co0 + sigf(gi0) * tanhfast(gg0);
        float cn1 = sigf(gf1) * co1 + sigf(gi1) * tanhfast(gg1);
        float h0 = sigf(go0) * tanhfast(cn0);
        float h1 = sigf(go1) * tanhfast(cn1);
        P.c2[n * 768 + mG] = cn0;
        P.c2[n * 768 + mG + 1] = cn1;
        unsigned pk = (unsigned)f2bf(h0) | ((unsigned)f2bf(h1) << 16);
        ATOMIC_ST((unsigned*)(P.Acat + n * AROW + wrbase + mG), pk);
      }
      setflag(cfl + 48 + local, (unsigned)(t + 1));   // g2done

      if (local < 32) {
        waitflags(cfl + 48, 48, (unsigned)(t + 1), tid);   // all gates2 of cluster
        // ---- F: FC partials (16 rows x 64 cols) ----
        ushort8* fst = sbuf + 1024;      // 24 KB A-stage (bytes 16K..40K)
        const int n0f = rowbase + (local >> 3) * 16, cg2 = local & 7, ctg = cg2 * 4 + w;
        const int h2rd = 768 + ((t + 1) & 1) * 768;
#pragma unroll
        for (int i = 0; i < 6; ++i) {    // coherent-stage h2 rows: [colblk][row]
          int cc = w * 6 + i;
          const u16* gp = P.Acat + (n0f + (l & 15)) * AROW + h2rd + cc * 32 + ((l >> 4) * 8);
          GLLDS_C(gp, &fst[cc * 64]);
        }
        asm volatile("s_waitcnt vmcnt(0)" ::: "memory");
        __syncthreads();
        const u16* bbase = P.W1p + ((long)ctg << 9) + l * 8;
        f32x4 facc = {};
#pragma unroll 6
        for (int kt = 0; kt < 24; ++kt) {
          ushort8 a = fst[kt * 64 + l];
          ushort8 bf8 = *reinterpret_cast<const ushort8*>(bbase + kt * 16384);
          facc = MFMA_B16(a, bf8, facc);
        }
        int col = ctg * 16 + (l & 15);
        float w2v = P.W2[col], b1v = P.b1[col];
        float pr[4];
#pragma unroll
        for (int reg = 0; reg < 4; ++reg) pr[reg] = fmaxf(facc[reg] + b1v, 0.f) * w2v;
#pragma unroll
        for (int mm = 1; mm < 16; mm <<= 1)
#pragma unroll
          for (int reg = 0; reg < 4; ++reg) pr[reg] += __shfl_xor(pr[reg], mm);
        if ((l & 15) == 0)
#pragma unroll
          for (int reg = 0; reg < 4; ++reg) fbuf[w][(l >> 4) * 4 + reg][0] = pr[reg];
        __syncthreads();
        if (tid < 16)
          ATOMIC_ST(P.pbuf + (n0f + tid) * 8 + cg2,
                    fbuf[0][tid][0] + fbuf[1][tid][0] + fbuf[2][tid][0] + fbuf[3][tid][0]);
        setflag(cfl + local, (unsigned)(t + 1));     // fdone
      }
    } else {
      // ---- g1p: 64 rows x 192 cols, K=768; epilogue folds bias + x-projection ----
      const int jb = local - 48;
      if (t < 127) {
        for (int p = tid; p < 512; p += 256)
          xsb[p >> 3][p & 7] = P.x[((rowbase + (p >> 3)) * LSEQ + t + 1) * 8 + (p & 7)];
      } else {
        for (int p = tid; p < 512; p += 256) xsb[p >> 3][p & 7] = 0.f;
      }
      __syncthreads();
      auto stage_g1 = [&](int kt, int slot) {
#pragma unroll
        for (int i = 0; i < 4; ++i) {
          int f = w * 4 + i;
          if (f < 4) {                               // A (mutable h1): coherent
            const u16* gp = P.Acat + (rowbase + f * 16 + (l & 15)) * AROW + kt * 32 + ((l >> 4) * 8);
            GLLDS_C(gp, &sbuf[(slot * 16 + f) * 64]);
          } else {                                   // B (weights): plain cached
            int jt_l = f - 4;
            const u16* gp = P.Bp1 + (((long)(kt * 192 + jb * 12 + jt_l)) << 9) + l * 8;
            GLLDS(gp, &sbuf[(slot * 16 + f) * 64]);
          }
        }
      };
      f32x4 acc[3][4] = {};
      stage_g1(0, 0);
      stage_g1(1, 1);
      for (int kt = 0; kt < 24; ++kt) {
        if (kt < 22) {
          stage_g1(kt + 2, (kt + 2) % 3);
          asm volatile("s_waitcnt vmcnt(8)" ::: "memory");
        } else if (kt == 22) {
          asm volatile("s_waitcnt vmcnt(4)" ::: "memory");
        } else {
          asm volatile("s_waitcnt vmcnt(0)" ::: "memory");
        }
        __builtin_amdgcn_s_barrier();
        __builtin_amdgcn_sched_barrier(0);
        const int base = (kt % 3) * 16;
        ushort8 a_[4];
#pragma unroll
        for (int rt = 0; rt < 4; ++rt) a_[rt] = sbuf[(base + rt) * 64 + l];
#pragma unroll
        for (int jj = 0; jj < 3; ++jj) {
          ushort8 bfr = sbuf[(base + 4 + w * 3 + jj) * 64 + l];
#pragma unroll
          for (int rt = 0; rt < 4; ++rt)
            acc[jj][rt] = MFMA_B16(a_[rt], bfr, acc[jj][rt]);
        }
        __builtin_amdgcn_sched_barrier(0);
        __builtin_amdgcn_s_barrier();
      }
      // epilogue: g1p = acc + bs1 + x(t+1) . W_ih1[:,0:8]  (coherent stores)
      float wc[3][8], bsv[3];
#pragma unroll
      for (int jj = 0; jj < 3; ++jj) {
        int col = (jb * 12 + w * 3 + jj) * 16 + (l & 15);
        bsv[jj] = P.bs1[col];
#pragma unroll
        for (int k = 0; k < 8; ++k) wc[jj][k] = P.Wih1t[k * 3072 + col];
      }
#pragma unroll
      for (int rt = 0; rt < 4; ++rt)
#pragma unroll
        for (int reg = 0; reg < 4; ++reg) {
          int rl = rt * 16 + (l >> 4) * 4 + reg;
          int n = rowbase + rl;
          float xv[8];
#pragma unroll
          for (int k = 0; k < 8; ++k) xv[k] = xsb[rl][k];
#pragma unroll
          for (int jj = 0; jj < 3; ++jj) {
            float v = acc[jj][rt][reg] + bsv[jj];
#pragma unroll
            for (int k = 0; k < 8; ++k) v += xv[k] * wc[jj][k];
            ATOMIC_ST(P.g1p + n * 3072 + (jb * 12 + w * 3 + jj) * 16 + (l & 15), v);
          }
        }
      setflag(cfl + 32 + jb, (unsigned)(t + 1));     // g1done

      waitflags(cfl, 48, (unsigned)(t + 1), tid);    // all fdone + g1done of cluster
      phase_H(P, t, tid, rowbase + jb * 4, xsb);
      setflag(cfl + 96 + jb, (unsigned)(t + 2));     // hdone
    }
  }
}

extern "C" void kernel_launch(void* const* d_in, const int* in_sizes, int n_in,
                              void* d_out, int out_size, void* d_ws, size_t ws_size,
                              hipStream_t stream) {
  const float* x    = (const float*)d_in[0];
  const float* Wih1 = (const float*)d_in[1];
  const float* bih1 = (const float*)d_in[2];
  const float* Whh1 = (const float*)d_in[3];
  const float* bhh1 = (const float*)d_in[4];
  const float* Wih2 = (const float*)d_in[5];
  const float* bih2 = (const float*)d_in[6];
  const float* Whh2 = (const float*)d_in[7];
  const float* bhh2 = (const float*)d_in[8];
  const float* W1   = (const float*)d_in[9];
  const float* b1   = (const float*)d_in[10];
  const float* W2   = (const float*)d_in[11];
  const float* b2   = (const float*)d_in[12];

  char* ws = (char*)d_ws;
  u16* Bp2 = (u16*)(ws + OFF_BP2);
  u16* Bp1 = (u16*)(ws + OFF_BP1);
  u16* W1p = (u16*)(ws + OFF_W1P);
  float* Wih1t = (float*)(ws + OFF_WIH1T);
  float* bs1 = (float*)(ws + OFF_BS1);
  float* bs2 = (float*)(ws + OFF_BS2);
  float* g1p = (float*)(ws + OFF_G1P);
  float* pbuf = (float*)(ws + OFF_PBUF);
  u16* Acat = (u16*)(ws + OFF_ACAT);
  float* c1 = (float*)(ws + OFF_C1);
  float* c2 = (float*)(ws + OFF_C2);
  float* sb = (float*)(ws + OFF_SB);
  unsigned* bar = (unsigned*)(ws + OFF_BAR);
  float* outs = (float*)d_out;
  float* stores = outs + N_B * LSEQ;

  pack_kernel<<<2048, 256, 0, stream>>>(Wih1, bih1, Whh1, bhh1, Wih2, bih2, Whh2, bhh2, W1,
                                        Bp2, Bp1, W1p, Wih1t, bs1, bs2);
  hipMemsetAsync(ws + OFF_ZERO, 0, ZERO_BYTES, stream);

  Params Pr = {x, Bp2, Bp1, W1p, Wih1t, bs1, bs2, b1, W2, b2,
               Acat, g1p, c1, c2, sb, pbuf, bar, outs, stores};
  lstm_fused<<<NBLK, 256, 0, stream>>>(Pr);
}

// Round 9
// 3820.159 us; speedup vs baseline: 1.2384x; 1.2384x over previous
//
#include <hip/hip_runtime.h>

typedef unsigned short u16;
typedef unsigned int u32;
typedef __attribute__((ext_vector_type(8))) unsigned short ushort8;
typedef __attribute__((ext_vector_type(4))) float f32x4;
typedef __attribute__((ext_vector_type(2))) float f32x2;
typedef __attribute__((ext_vector_type(4))) unsigned int u32x4;
typedef __attribute__((ext_vector_type(8))) __bf16 bf16x8;

#define N_B 256
#define LSEQ 128
#define AROW 2304   // 768 (h1) + 2*768 (h2 double-buffer phases)
#define NBLK 256

#define MFMA_B16(a, b, c) __builtin_amdgcn_mfma_f32_16x16x32_bf16( \
    __builtin_bit_cast(bf16x8, a), __builtin_bit_cast(bf16x8, b), c, 0, 0, 0)

// plain cached staging (read-only weights)
#define GLLDS(gp, lp) __builtin_amdgcn_global_load_lds( \
    (const __attribute__((address_space(1))) void*)(gp), \
    (__attribute__((address_space(3))) void*)(lp), 16, 0, 0)
// coherent staging (mutable cross-block data): aux=17 = sc0|sc1
#define GLLDS_C(gp, lp) __builtin_amdgcn_global_load_lds( \
    (const __attribute__((address_space(1))) void*)(gp), \
    (__attribute__((address_space(3))) void*)(lp), 16, 0, 17)

#define ATOMIC_LD(p) __hip_atomic_load((p), __ATOMIC_RELAXED, __HIP_MEMORY_SCOPE_AGENT)
#define ATOMIC_ST(p, v) __hip_atomic_store((p), (v), __ATOMIC_RELAXED, __HIP_MEMORY_SCOPE_AGENT)

// 16B coherent (sc0|sc1) vector store: write-through to the MALL coherence point
__device__ __forceinline__ void st16_sc(void* p, u32x4 v) {
  asm volatile("global_store_dwordx4 %0, %1, off sc0 sc1" :: "v"(p), "v"(v) : "memory");
}

// ---- workspace layout (byte offsets) ----
#define OFF_BP2   0ull
#define SZ_BP2    (48ull*192*512*2)
#define OFF_BP1   (OFF_BP2 + SZ_BP2)
#define SZ_BP1    (24ull*192*512*2)
#define OFF_W1P   (OFF_BP1 + SZ_BP1)
#define SZ_W1P    (24ull*32*512*2)
#define OFF_WIH1T (OFF_W1P + SZ_W1P)
#define SZ_WIH1T  (9ull*3072*4)
#define OFF_BS1   (OFF_WIH1T + SZ_WIH1T)
#define OFF_BS2   (OFF_BS1 + 3072*4)
#define OFF_W8Q   (OFF_BS2 + 3072*4)       // Wih1 row 8, quad-interleaved [c][q]
#define OFF_G1P   (OFF_W8Q + 3072*4)       // quad-interleaved [n][c 0..767][q 0..3] fp32
#define SZ_G1P    (256ull*3072*4)
#define OFF_PBUF  (OFF_G1P + SZ_G1P)
#define SZ_PBUF   (256ull*8*4)
#define OFF_ZERO  (OFF_PBUF + SZ_PBUF)
#define OFF_ACAT  OFF_ZERO
#define SZ_ACAT   (256ull*2304*2)
#define OFF_C1    (OFF_ACAT + SZ_ACAT)
#define OFF_C2    (OFF_C1 + 256ull*768*4)
#define OFF_SB    (OFF_C2 + 256ull*768*4)
#define OFF_BAR   (OFF_SB + 1024)          // flags: 4 clusters x 128 uints at bar+32
#define SZ_BAR    (128 + 256*32*4)
#define OFF_END   (OFF_BAR + SZ_BAR)
#define ZERO_BYTES (OFF_END - OFF_ZERO)

__device__ __forceinline__ float sigf(float v) { return 1.f / (1.f + __expf(-v)); }
__device__ __forceinline__ float tanhfast(float v) { return 1.f - 2.f / (__expf(2.f * v) + 1.f); }
__device__ __forceinline__ u16 f2bf(float f) {
  union { float f; unsigned u; } v; v.f = f;
  unsigned r = v.u + 0x7fffu + ((v.u >> 16) & 1u);   // round-to-nearest-even
  return (u16)(r >> 16);
}

struct Params {
  const float* x;
  const u16* Bp2; const u16* Bp1; const u16* W1p;
  const float* Wih1t; const float* bs1; const float* bs2; const float* w8q;
  const float* b1; const float* W2; const float* b2;
  u16* Acat; float* g1q; float* c1; float* c2; float* sb; float* pbuf;
  unsigned* bar;
  float* outs; float* stores;
};

// ---------------------------------------------------------------------------
// Flag sync (round 6/7-proven protocol, DENSE flags: one poll = one coalesced
// 256B MALL read). setflag: vmcnt(0) drain of this block's sc1 data stores ->
// syncthreads -> relaxed sc1 flag store. waitflags: wave 0 polls (relaxed
// sc1, no cache maintenance anywhere), then syncthreads. Per-cluster layout
// (cfl = bar+32+c*128): [0..47]=g2done [48..63]=g1done [64..95]=fdone
// [96..111]=hdone. All values monotone counters.
// ---------------------------------------------------------------------------
__device__ __forceinline__ void waitflags(const unsigned* f, int n, unsigned target, int tid) {
  if (tid < 64) {
    for (;;) {
      unsigned v = (tid < n) ? ATOMIC_LD(f + tid) : target;
      if (__all((int)(v >= target))) break;
      __builtin_amdgcn_s_sleep(1);
    }
  }
  __syncthreads();
}
__device__ __forceinline__ void setflag(unsigned* f, unsigned v) {
  asm volatile("s_waitcnt vmcnt(0)" ::: "memory");
  __syncthreads();
  if (threadIdx.x == 0) ATOMIC_ST(f, v);
}

// ---------------------------------------------------------------------------
// One-time packing (round-1 verified layouts + w8q).
// ---------------------------------------------------------------------------
__global__ void pack_kernel(const float* __restrict__ Wih1, const float* __restrict__ bih1,
                            const float* __restrict__ Whh1, const float* __restrict__ bhh1,
                            const float* __restrict__ Wih2, const float* __restrict__ bih2,
                            const float* __restrict__ Whh2, const float* __restrict__ bhh2,
                            const float* __restrict__ W1,
                            u16* __restrict__ Bp2, u16* __restrict__ Bp1, u16* __restrict__ W1p,
                            float* __restrict__ Wih1t, float* __restrict__ bs1,
                            float* __restrict__ bs2, float* __restrict__ w8q) {
  const long NB2 = 48l * 192 * 512, NB1 = 24l * 192 * 512, NW1 = 24l * 32 * 512, NT = 9l * 3072;
  const long total = NB2 + NB1 + NW1 + NT + 3072 * 3;
  for (long idx = (long)blockIdx.x * 256 + threadIdx.x; idx < total; idx += (long)gridDim.x * 256) {
    if (idx < NB2) {                       // Wcat2 = [W_ih2 ; W_hh2] (K=1536)
      long kt = idx / (192 * 512); long r = idx % (192 * 512);
      int jt = (int)(r / 512); int s = (int)(r % 512);
      int ll = s >> 3, e = s & 7;
      int k = (int)kt * 32 + ((ll >> 4) * 8) + e;
      int j = jt * 16 + (ll & 15);
      float v = (k < 768) ? Wih2[j * 768 + k] : Whh2[j * 768 + k - 768];
      Bp2[idx] = f2bf(v);
    } else if (idx < NB2 + NB1) {          // W_hh1 (K=768)
      long i = idx - NB2;
      long kt = i / (192 * 512); long r = i % (192 * 512);
      int jt = (int)(r / 512); int s = (int)(r % 512);
      int ll = s >> 3, e = s & 7;
      int k = (int)kt * 32 + ((ll >> 4) * 8) + e;
      int j = jt * 16 + (ll & 15);
      Bp1[i] = f2bf(Whh1[j * 768 + k]);
    } else if (idx < NB2 + NB1 + NW1) {    // W1 (K=768, N=512)
      long i = idx - NB2 - NB1;
      long kt = i / (32 * 512); long r = i % (32 * 512);
      int jt = (int)(r / 512); int s = (int)(r % 512);
      int ll = s >> 3, e = s & 7;
      int k = (int)kt * 32 + ((ll >> 4) * 8) + e;
      int j = jt * 16 + (ll & 15);
      W1p[i] = f2bf(W1[j * 768 + k]);
    } else if (idx < NB2 + NB1 + NW1 + NT) {  // W_ih1 transposed (fp32)
      long i = idx - NB2 - NB1 - NW1;
      int k = (int)(i / 3072), j = (int)(i % 3072);
      Wih1t[i] = Wih1[j * 9 + k];
    } else {
      long i = idx - NB2 - NB1 - NW1 - NT;
      if (i < 3072) bs1[i] = bih1[i] + bhh1[i];
      else if (i < 6144) { long j = i - 3072; bs2[j] = bih2[j] + bhh2[j]; }
      else {                               // w8q[c*4+q] = Wih1[(q*768+c)*9 + 8]
        long cq = i - 6144; int cc = (int)(cq >> 2), q = (int)(cq & 3);
        w8q[cq] = Wih1[(q * 768 + cc) * 9 + 8];
      }
    }
  }
}

// ---------------------------------------------------------------------------
// Persistent kernel: 4 independent 64-row clusters x 64 blocks.
//   local 0..47 : gates2 (h2-half early-start) + h2/c2; local 0..31 also F.
//   local 48..63: g1p (quad-interleaved out) + H (4 rows: out/cs/h1-act).
// All cross-block data sc1-vectorized; no cache-wide maintenance anywhere.
// ---------------------------------------------------------------------------
__global__ __launch_bounds__(256) void lstm_fused(Params P) {
  __shared__ ushort8 sbuf[48 * 64];     // 48 KB staging / g1p mirror (H)
  __shared__ float xsb[64][8];          // 2 KB x rows
  __shared__ float csh[8];
  float (*fbuf)[64][16] = (float(*)[64][16])sbuf;  // 16 KB overlay, post-K-loop only
  const int tid = threadIdx.x, l = tid & 63, w = tid >> 6;
  const int bid = blockIdx.x;
  const int c = bid >> 6, local = bid & 63;
  const int rowbase = c * 64;
  unsigned* cfl = P.bar + 32 + c * 128;

  if (local < 48) {
    // ================= gates2 (+F) blocks =================
    const int mg = local;
    setflag(cfl + local, 1u);                        // bootstrap: h2(-1)=0 published
    for (int t = 0; t < 128; ++t) {
      const int rdbase = 768 + (t & 1) * 768;        // h2(t-1)
      const int wrbase = 768 + ((t + 1) & 1) * 768;  // h2(t)
      auto stage_g2 = [&](int kc, int slot) {
#pragma unroll
        for (int i = 0; i < 4; ++i) {
          int f = w * 4 + i;
          if (f < 8) {                               // A (mutable): coherent
            int kt2 = f >> 2, rt = f & 3, kt = kc * 2 + kt2;
            int col = (kt >= 24) ? (rdbase + (kt - 24) * 32 + ((l >> 4) * 8))
                                 : (kt * 32 + ((l >> 4) * 8));
            const u16* gp = P.Acat + (rowbase + rt * 16 + (l & 15)) * AROW + col;
            GLLDS_C(gp, &sbuf[(slot * 16 + f) * 64]);
          } else {                                   // B (weights): plain cached
            int g = f - 8, kt2 = g >> 2, q = g & 3, kt = kc * 2 + kt2;
            const u16* gp = P.Bp2 + (((long)(kt * 192 + q * 48 + mg)) << 9) + l * 8;
            GLLDS(gp, &sbuf[(slot * 16 + f) * 64]);
          }
        }
      };
      auto kc_of = [](int g) { int k = g + 12; return (k >= 24) ? k - 24 : k; };
      // h2-half (kc 12..23) needs only g2flags(t-1); h1-half waits hdone mid-loop
      waitflags(cfl, 48, (unsigned)(t + 1), tid);
      f32x4 acc[4] = {};
      stage_g2(kc_of(0), 0);
      stage_g2(kc_of(1), 1);
      for (int g = 0; g < 24; ++g) {
        if (g < 22) {
          if (g == 10) waitflags(cfl + 96, 16, (unsigned)(t + 1), tid);  // h1(t) ready
          stage_g2(kc_of(g + 2), (g + 2) % 3);
          asm volatile("s_waitcnt vmcnt(8)" ::: "memory");
        } else if (g == 22) {
          asm volatile("s_waitcnt vmcnt(4)" ::: "memory");
        } else {
          asm volatile("s_waitcnt vmcnt(0)" ::: "memory");
        }
        __builtin_amdgcn_s_barrier();
        __builtin_amdgcn_sched_barrier(0);
        const int base = (g % 3) * 16;
#pragma unroll
        for (int kt2 = 0; kt2 < 2; ++kt2) {
          ushort8 bfr = sbuf[(base + 8 + kt2 * 4 + w) * 64 + l];
#pragma unroll
          for (int rt = 0; rt < 4; ++rt) {
            ushort8 a = sbuf[(base + kt2 * 4 + rt) * 64 + l];
            acc[rt] = MFMA_B16(a, bfr, acc[rt]);
          }
        }
        __builtin_amdgcn_sched_barrier(0);
        __builtin_amdgcn_s_barrier();
      }
      // epilogue: quadrant exchange -> h2/c2; vectorized sc1 h2 stores (16B)
#pragma unroll
      for (int rt = 0; rt < 4; ++rt)
#pragma unroll
        for (int reg = 0; reg < 4; ++reg) {
          int rl = rt * 16 + (l >> 4) * 4 + reg;
          fbuf[w][rl][l & 15] = acc[rt][reg] + P.bs2[w * 768 + mg * 16 + (l & 15)];
        }
      __syncthreads();
      for (int p = tid; p < 128; p += 256) {         // 64 rows x 2 col-octets
        int r = p >> 1, half = p & 1;
        int n = rowbase + r, mG = mg * 16 + half * 8;
        f32x4 cold0 = *(const f32x4*)(P.c2 + n * 768 + mG);
        f32x4 cold1 = *(const f32x4*)(P.c2 + n * 768 + mG + 4);
        u32 hp[4];
        f32x4 cnew0, cnew1;
#pragma unroll
        for (int k = 0; k < 8; ++k) {
          int pp = half * 8 + k;
          float gi = fbuf[0][r][pp], gf = fbuf[1][r][pp], gg = fbuf[2][r][pp], go = fbuf[3][r][pp];
          float co = (k < 4) ? cold0[k] : cold1[k - 4];
          float cn = sigf(gf) * co + sigf(gi) * tanhfast(gg);
          float h = sigf(go) * tanhfast(cn);
          if (k < 4) cnew0[k] = cn; else cnew1[k - 4] = cn;
          if (k & 1) hp[k >> 1] |= ((u32)f2bf(h)) << 16; else hp[k >> 1] = f2bf(h);
        }
        *(f32x4*)(P.c2 + n * 768 + mG) = cnew0;
        *(f32x4*)(P.c2 + n * 768 + mG + 4) = cnew1;
        st16_sc(P.Acat + n * AROW + wrbase + mG, *(u32x4*)hp);
      }
      setflag(cfl + local, (unsigned)(t + 2));       // g2done

      if (local < 32) {
        // ---- F: FC partials (16 rows x 64 cols) ----
        waitflags(cfl, 48, (unsigned)(t + 2), tid);
        ushort8* fst = sbuf + 1024;                  // 24 KB region [16:40KB)
        const int n0f = rowbase + (local >> 3) * 16, cg2 = local & 7, ctg = cg2 * 4 + w;
        const int h2rd = 768 + ((t + 1) & 1) * 768;
#pragma unroll
        for (int i = 0; i < 6; ++i) {
          int cc = w * 6 + i;
          const u16* gp = P.Acat + (n0f + (l & 15)) * AROW + h2rd + cc * 32 + ((l >> 4) * 8);
          GLLDS_C(gp, &fst[cc * 64]);
        }
        asm volatile("s_waitcnt vmcnt(0)" ::: "memory");
        __syncthreads();
        const u16* bbase = P.W1p + ((long)ctg << 9) + l * 8;
        f32x4 facc = {};
#pragma unroll 6
        for (int kt = 0; kt < 24; ++kt) {
          ushort8 a = fst[kt * 64 + l];
          ushort8 bf8 = *reinterpret_cast<const ushort8*>(bbase + kt * 16384);
          facc = MFMA_B16(a, bf8, facc);
        }
        int col = ctg * 16 + (l & 15);
        float w2v = P.W2[col], b1v = P.b1[col];
        float pr[4];
#pragma unroll
        for (int reg = 0; reg < 4; ++reg) pr[reg] = fmaxf(facc[reg] + b1v, 0.f) * w2v;
#pragma unroll
        for (int mm = 1; mm < 16; mm <<= 1)
#pragma unroll
          for (int reg = 0; reg < 4; ++reg) pr[reg] += __shfl_xor(pr[reg], mm);
        if ((l & 15) == 0)
#pragma unroll
          for (int reg = 0; reg < 4; ++reg) fbuf[w][(l >> 4) * 4 + reg][0] = pr[reg];
        __syncthreads();
        if (tid < 16)
          ATOMIC_ST(P.pbuf + (n0f + tid) * 8 + cg2,
                    fbuf[0][tid][0] + fbuf[1][tid][0] + fbuf[2][tid][0] + fbuf[3][tid][0]);
        setflag(cfl + 64 + local, (unsigned)(t + 2));  // fdone
      }
    }
  } else {
    // ================= g1p + H blocks =================
    const int jb = local - 48;
    const int n0 = rowbase + jb * 4;
    const int quad = jb >> 2;                        // this block's gate quadrant
    for (int t = -1; t < 128; ++t) {
      // ---- g1p(t): 64 rows x 192 cols (quad-interleaved out); t=-1: bias+x only ----
      if (t < 127) {
        if (t >= 0) waitflags(cfl + 96, 16, (unsigned)(t + 1), tid);   // h1(t) ready
        for (int p = tid; p < 512; p += 256)
          xsb[p >> 3][p & 7] = P.x[((rowbase + (p >> 3)) * LSEQ + t + 1) * 8 + (p & 7)];
        __syncthreads();
        f32x4 acc[3][4] = {};
        if (t >= 0) {
          auto stage_g1 = [&](int kt, int slot) {
#pragma unroll
            for (int i = 0; i < 4; ++i) {
              int f = w * 4 + i;
              if (f < 4) {                           // A (mutable h1): coherent
                const u16* gp = P.Acat + (rowbase + f * 16 + (l & 15)) * AROW + kt * 32 + ((l >> 4) * 8);
                GLLDS_C(gp, &sbuf[(slot * 16 + f) * 64]);
              } else {                               // B (weights): plain cached
                int jt_l = f - 4;
                const u16* gp = P.Bp1 + (((long)(kt * 192 + jb * 12 + jt_l)) << 9) + l * 8;
                GLLDS(gp, &sbuf[(slot * 16 + f) * 64]);
              }
            }
          };
          stage_g1(0, 0);
          stage_g1(1, 1);
          for (int kt = 0; kt < 24; ++kt) {
            if (kt < 22) {
              stage_g1(kt + 2, (kt + 2) % 3);
              asm volatile("s_waitcnt vmcnt(8)" ::: "memory");
            } else if (kt == 22) {
              asm volatile("s_waitcnt vmcnt(4)" ::: "memory");
            } else {
              asm volatile("s_waitcnt vmcnt(0)" ::: "memory");
            }
            __builtin_amdgcn_s_barrier();
            __builtin_amdgcn_sched_barrier(0);
            const int base = (kt % 3) * 16;
            ushort8 a_[4];
#pragma unroll
            for (int rt = 0; rt < 4; ++rt) a_[rt] = sbuf[(base + rt) * 64 + l];
#pragma unroll
            for (int jj = 0; jj < 3; ++jj) {
              ushort8 bfr = sbuf[(base + 4 + w * 3 + jj) * 64 + l];
#pragma unroll
              for (int rt = 0; rt < 4; ++rt)
                acc[jj][rt] = MFMA_B16(a_[rt], bfr, acc[jj][rt]);
            }
            __builtin_amdgcn_sched_barrier(0);
            __builtin_amdgcn_s_barrier();
          }
        }
        // epilogue: v = acc + bs1 + x(t+1) dot Wih1[:,0:8]; store quad-interleaved
        float wc[3][8], bsv[3];
#pragma unroll
        for (int jj = 0; jj < 3; ++jj) {
          int ct = jb * 12 + w * 3 + jj;
          int col = ct * 16 + (l & 15);
          bsv[jj] = P.bs1[col];
#pragma unroll
          for (int k = 0; k < 8; ++k) wc[jj][k] = P.Wih1t[k * 3072 + col];
        }
#pragma unroll
        for (int rt = 0; rt < 4; ++rt)
#pragma unroll
          for (int reg = 0; reg < 4; ++reg) {
            int rl = rt * 16 + (l >> 4) * 4 + reg;
            int n = rowbase + rl;
            float xv[8];
#pragma unroll
            for (int k = 0; k < 8; ++k) xv[k] = xsb[rl][k];
#pragma unroll
            for (int jj = 0; jj < 3; ++jj) {
              int ct = jb * 12 + w * 3 + jj;
              int cin = (ct - quad * 48) * 16 + (l & 15);       // col within quadrant
              float v = acc[jj][rt][reg] + bsv[jj];
#pragma unroll
              for (int k = 0; k < 8; ++k) v += xv[k] * wc[jj][k];
              ATOMIC_ST(P.g1q + n * 3072 + cin * 4 + quad, v);
            }
          }
        setflag(cfl + 48 + jb, (unsigned)(t + 2));   // g1done
      }

      // ---- H(t): out(t) (t>=0), cs(t+1)/h1(t+1) act (t<127) ----
      if (t < 127) {
        waitflags(cfl + 48, 16, (unsigned)(t + 2), tid);   // all g1done
        // stage 48KB g1q rows n0..n0+3 (contiguous) into LDS mirror
#pragma unroll
        for (int i = 0; i < 12; ++i) {
          int f = w * 12 + i;
          const float* gp = P.g1q + n0 * 3072 + f * 256 + l * 4;
          GLLDS_C(gp, (char*)sbuf + f * 1024);
        }
      }
      float ov = 0.f;
      if (t >= 0) {
        waitflags(cfl + 64, 32, (unsigned)(t + 2), tid);   // all fdone
        if (tid < 4) {
          int n = n0 + tid;
          float pb[8];
#pragma unroll
          for (int i = 0; i < 8; ++i) pb[i] = ATOMIC_LD(P.pbuf + n * 8 + i);
          ov = ((pb[0] + pb[1]) + (pb[2] + pb[3])) + ((pb[4] + pb[5]) + (pb[6] + pb[7])) + P.b2[0];
          P.outs[n * LSEQ + t] = ov;
        }
      }
      if (t < 127) {
        if (tid < 4) {
          int n = n0 + tid;
          float cs = P.sb[n] + P.x[(n * LSEQ + t + 1) * 8] - ov;   // exact fp32
          P.sb[n] = cs;
          P.stores[n * LSEQ + t + 1] = cs;
          csh[tid] = cs;
        }
        asm volatile("s_waitcnt vmcnt(0)" ::: "memory");
        __syncthreads();
        // act: 4 rows x 768 cols; LDS mirror holds [row][col][quad] fp32
        const int r = tid >> 6, l2 = tid & 63;
        const int n = n0 + r;
        const float* ldsrow = (const float*)sbuf + r * 3072;
        float cs = csh[r];
#pragma unroll
        for (int ci = 0; ci < 6; ++ci) {
          int m = ci * 128 + l2 * 2;
          f32x4 qa = *(const f32x4*)(ldsrow + m * 4);
          f32x4 qb = *(const f32x4*)(ldsrow + m * 4 + 4);
          f32x4 wa = *(const f32x4*)(P.w8q + m * 4);
          f32x4 wb = *(const f32x4*)(P.w8q + m * 4 + 4);
          float ga[4], gb[4];
#pragma unroll
          for (int q = 0; q < 4; ++q) { ga[q] = qa[q] + cs * wa[q]; gb[q] = qb[q] + cs * wb[q]; }
          f32x2 co = *(const f32x2*)(P.c1 + n * 768 + m);
          float cn0 = sigf(ga[1]) * co.x + sigf(ga[0]) * tanhfast(ga[2]);
          float cn1 = sigf(gb[1]) * co.y + sigf(gb[0]) * tanhfast(gb[2]);
          float h0 = sigf(ga[3]) * tanhfast(cn0);
          float h1 = sigf(gb[3]) * tanhfast(cn1);
          f32x2 cn; cn.x = cn0; cn.y = cn1;
          *(f32x2*)(P.c1 + n * 768 + m) = cn;
          u32 pk = (u32)f2bf(h0) | ((u32)f2bf(h1) << 16);
          ATOMIC_ST((u32*)(P.Acat + n * AROW + m), pk);
        }
        setflag(cfl + 96 + jb, (unsigned)(t + 2));   // hdone
      }
    }
  }
}

extern "C" void kernel_launch(void* const* d_in, const int* in_sizes, int n_in,
                              void* d_out, int out_size, void* d_ws, size_t ws_size,
                              hipStream_t stream) {
  const float* x    = (const float*)d_in[0];
  const float* Wih1 = (const float*)d_in[1];
  const float* bih1 = (const float*)d_in[2];
  const float* Whh1 = (const float*)d_in[3];
  const float* bhh1 = (const float*)d_in[4];
  const float* Wih2 = (const float*)d_in[5];
  const float* bih2 = (const float*)d_in[6];
  const float* Whh2 = (const float*)d_in[7];
  const float* bhh2 = (const float*)d_in[8];
  const float* W1   = (const float*)d_in[9];
  const float* b1   = (const float*)d_in[10];
  const float* W2   = (const float*)d_in[11];
  const float* b2   = (const float*)d_in[12];

  char* ws = (char*)d_ws;
  u16* Bp2 = (u16*)(ws + OFF_BP2);
  u16* Bp1 = (u16*)(ws + OFF_BP1);
  u16* W1p = (u16*)(ws + OFF_W1P);
  float* Wih1t = (float*)(ws + OFF_WIH1T);
  float* bs1 = (float*)(ws + OFF_BS1);
  float* bs2 = (float*)(ws + OFF_BS2);
  float* w8q = (float*)(ws + OFF_W8Q);
  float* g1q = (float*)(ws + OFF_G1P);
  float* pbuf = (float*)(ws + OFF_PBUF);
  u16* Acat = (u16*)(ws + OFF_ACAT);
  float* c1 = (float*)(ws + OFF_C1);
  float* c2 = (float*)(ws + OFF_C2);
  float* sb = (float*)(ws + OFF_SB);
  unsigned* bar = (unsigned*)(ws + OFF_BAR);
  float* outs = (float*)d_out;
  float* stores = outs + N_B * LSEQ;

  pack_kernel<<<2048, 256, 0, stream>>>(Wih1, bih1, Whh1, bhh1, Wih2, bih2, Whh2, bhh2, W1,
                                        Bp2, Bp1, W1p, Wih1t, bs1, bs2, w8q);
  (void)hipMemsetAsync(ws + OFF_ZERO, 0, ZERO_BYTES, stream);

  Params Pr = {x, Bp2, Bp1, W1p, Wih1t, bs1, bs2, w8q, b1, W2, b2,
               Acat, g1q, c1, c2, sb, pbuf, bar, outs, stores};
  lstm_fused<<<NBLK, 256, 0, stream>>>(Pr);
}